// Round 1
// baseline (34.704 us; speedup 1.0000x reference)
//
#include <hip/hip_runtime.h>
#include <hip/hip_bf16.h>

#define NB 64
#define NV 64
#define ND 64
#define NH 64
#define NE 4032   // V*(V-1)
#define OUTW 128  // D + H

typedef __bf16 bf16_t;
typedef bf16_t bf16x8 __attribute__((ext_vector_type(8)));
typedef float f32x4 __attribute__((ext_vector_type(4)));

// ---------------------------------------------------------------------------
// Kernel 0: pre-pack W1[1][:,64:128] and W2[1] into per-lane MFMA B-fragment
// order (bf16), so the main kernel loads them as broadcast 16B reads.
// Fragment layout for mfma_f32_16x16x32_bf16 B-operand:
//   B[k][n], n = 16*nt + (lane&15), k = 32*ks + 8*(lane>>4) + j, j=0..7
// Stored flat: [((nt*2+ks)*64 + lane)*8 + j]
// ---------------------------------------------------------------------------
__global__ void prep_weights(const float* __restrict__ W1,
                             const float* __restrict__ W2,
                             bf16_t* __restrict__ wf1,
                             bf16_t* __restrict__ wf2) {
    int t = blockIdx.x * blockDim.x + threadIdx.x;
    if (t >= 8192) return;
    if (t < 4096) {
        int j = t & 7, lane = (t >> 3) & 63, ks = (t >> 9) & 1, nt = (t >> 10) & 3;
        int n = 16 * nt + (lane & 15);
        int f = 64 + 32 * ks + 8 * (lane >> 4) + j;   // x_send half of W1
        wf1[t] = (bf16_t)W1[(NH + n) * (2 * ND) + f]; // W1[1][n][f]
    } else {
        int u = t - 4096;
        int j = u & 7, lane = (u >> 3) & 63, ks = (u >> 9) & 1, nt = (u >> 10) & 3;
        int n = 16 * nt + (lane & 15);
        int h = 32 * ks + 8 * (lane >> 4) + j;
        wf2[u] = (bf16_t)W2[(NH + n) * NH + h];       // W2[1][n][h]
    }
}

// ---------------------------------------------------------------------------
// Main kernel: one block per (b, r).  M = 64 rows = 63 senders + 1 pad row
// (weight 0).  4 waves, wave w owns rows 16w..16w+15.
//   msg1 = relu(W1a·x_r + W1b·x_s + b1[1])   (W1a·x_r hoisted per block)
//   msg2 = relu(msg1·W2[1]^T + b2[1])
//   agg[b,r,:] = sum_m msg2[m,:] * edges[b, e(m), 1]
// ---------------------------------------------------------------------------
__global__ void gnn_main(const float* __restrict__ inputs,
                         const float* __restrict__ edges,
                         const float* __restrict__ W1,
                         const float* __restrict__ b1,
                         const float* __restrict__ b2,
                         const bf16_t* __restrict__ wf1,
                         const bf16_t* __restrict__ wf2,
                         float* __restrict__ out) {
    __shared__ float w_lds[64];
    __shared__ float yr_lds[64];
    __shared__ __align__(16) bf16_t msg1_lds[64][80]; // stride 80 bf16 = 160B (16B aligned)
    __shared__ float agg_lds[4][64];

    const int bid = blockIdx.x;
    const int b = bid >> 6, r = bid & 63;
    const int tid = threadIdx.x;
    const int lane = tid & 63, wid = tid >> 6;
    const int lr = lane & 15, lg = lane >> 4;

    const float* xb = inputs + b * NV * ND;
    const float* xr = xb + r * ND;

    // ---- Phase 0: edge weights per row + y_r = W1a · x_r (bf16-rounded, f32 acc)
    if (tid < 64) {
        const int m0 = tid;
        float w = 0.f;
        if (m0 < 63) {
            const int s0 = (m0 < r) ? m0 : m0 + 1;
            const int e = s0 * 63 + r - (s0 < r ? 1 : 0);
            w = edges[(b * NE + e) * 2 + 1];
        }
        w_lds[m0] = w;

        const float* w1row = W1 + (NH + m0) * (2 * ND);  // W1[1][h=m0][:]
        float acc = 0.f;
        #pragma unroll
        for (int f = 0; f < ND; f += 4) {
            f32x4 wv = *(const f32x4*)(w1row + f);
            f32x4 xv = *(const f32x4*)(xr + f);
            #pragma unroll
            for (int q = 0; q < 4; ++q)
                acc += (float)(bf16_t)wv[q] * (float)(bf16_t)xv[q];
        }
        yr_lds[m0] = acc;
    }
    __syncthreads();

    // ---- GEMM1': A = x_send features (rows m), B = packed W1b fragments
    const int m = 16 * wid + lr;
    const int s = (m < r) ? m : (m == 63 ? r : m + 1);  // pad row reads x_r, weight 0
    const float* xs = xb + s * ND;

    bf16x8 a1[2];
    #pragma unroll
    for (int ks = 0; ks < 2; ++ks) {
        const float* p = xs + 32 * ks + 8 * lg;
        f32x4 v0 = *(const f32x4*)p;
        f32x4 v1 = *(const f32x4*)(p + 4);
        bf16x8 a;
        #pragma unroll
        for (int q = 0; q < 4; ++q) { a[q] = (bf16_t)v0[q]; a[4 + q] = (bf16_t)v1[q]; }
        a1[ks] = a;
    }

    f32x4 acc1[4];
    #pragma unroll
    for (int nt = 0; nt < 4; ++nt) {
        const float base = yr_lds[16 * nt + lr] + b1[NH + 16 * nt + lr];
        acc1[nt] = (f32x4){base, base, base, base};
    }
    #pragma unroll
    for (int nt = 0; nt < 4; ++nt) {
        #pragma unroll
        for (int ks = 0; ks < 2; ++ks) {
            const bf16x8 wb = *(const bf16x8*)(wf1 + ((nt * 2 + ks) * 64 + lane) * 8);
            acc1[nt] = __builtin_amdgcn_mfma_f32_16x16x32_bf16(a1[ks], wb, acc1[nt], 0, 0, 0);
        }
    }

    // relu -> bf16 -> LDS (re-fragment for GEMM2).  D layout: col=lane&15, row=lg*4+j
    #pragma unroll
    for (int nt = 0; nt < 4; ++nt) {
        #pragma unroll
        for (int j = 0; j < 4; ++j) {
            float v = acc1[nt][j];
            v = v > 0.f ? v : 0.f;
            msg1_lds[16 * wid + lg * 4 + j][16 * nt + lr] = (bf16_t)v;
        }
    }
    __syncthreads();

    // ---- GEMM2: A = msg1 rows (this wave's tile), B = packed W2 fragments
    bf16x8 a2[2];
    #pragma unroll
    for (int ks = 0; ks < 2; ++ks)
        a2[ks] = *(const bf16x8*)(&msg1_lds[16 * wid + lr][32 * ks + 8 * lg]);

    f32x4 acc2[4];
    #pragma unroll
    for (int nt = 0; nt < 4; ++nt) {
        const float base = b2[NH + 16 * nt + lr];
        acc2[nt] = (f32x4){base, base, base, base};
    }
    #pragma unroll
    for (int nt = 0; nt < 4; ++nt) {
        #pragma unroll
        for (int ks = 0; ks < 2; ++ks) {
            const bf16x8 wb = *(const bf16x8*)(wf2 + ((nt * 2 + ks) * 64 + lane) * 8);
            acc2[nt] = __builtin_amdgcn_mfma_f32_16x16x32_bf16(a2[ks], wb, acc2[nt], 0, 0, 0);
        }
    }

    // relu * edge_weight, reduce over the 16 rows of this wave's tile
    #pragma unroll
    for (int nt = 0; nt < 4; ++nt) {
        float sum = 0.f;
        #pragma unroll
        for (int j = 0; j < 4; ++j) {
            float v = acc2[nt][j];
            v = v > 0.f ? v : 0.f;
            sum += v * w_lds[16 * wid + lg * 4 + j];
        }
        sum += __shfl_xor(sum, 16);
        sum += __shfl_xor(sum, 32);
        if (lane < 16) agg_lds[wid][16 * nt + lane] = sum;
    }
    __syncthreads();

    // ---- Epilogue: cross-wave sum + output concat [x_r | agg]
    if (tid < 64) {
        float a = agg_lds[0][tid] + agg_lds[1][tid] + agg_lds[2][tid] + agg_lds[3][tid];
        float* o = out + (b * NV + r) * OUTW;
        o[tid] = xr[tid];
        o[ND + tid] = a;
    }
}

extern "C" void kernel_launch(void* const* d_in, const int* in_sizes, int n_in,
                              void* d_out, int out_size, void* d_ws, size_t ws_size,
                              hipStream_t stream) {
    const float* inputs = (const float*)d_in[0];
    const float* edges  = (const float*)d_in[1];
    const float* W1     = (const float*)d_in[2];
    const float* b1     = (const float*)d_in[3];
    const float* W2     = (const float*)d_in[4];
    const float* b2     = (const float*)d_in[5];
    // d_in[6]/d_in[7] (send_idx/recv_idx) are derived analytically.

    bf16_t* wf1 = (bf16_t*)d_ws;
    bf16_t* wf2 = wf1 + 4096;
    float* out = (float*)d_out;

    prep_weights<<<32, 256, 0, stream>>>(W1, W2, wf1, wf2);
    gnn_main<<<NB * NV, 256, 0, stream>>>(inputs, edges, W1, b1, b2, wf1, wf2, out);
}

// Round 2
// 23.891 us; speedup vs baseline: 1.4526x; 1.4526x over previous
//
#include <hip/hip_runtime.h>
#include <hip/hip_bf16.h>

#define NB 64
#define NV 64
#define ND 64
#define NH 64
#define NE 4032   // V*(V-1)
#define OUTW 128  // D + H

typedef __bf16 bf16_t;
typedef bf16_t bf16x8 __attribute__((ext_vector_type(8)));
typedef float f32x4 __attribute__((ext_vector_type(4)));

// ---------------------------------------------------------------------------
// prep2: blocks 0..63 compute, for batch b:
//   Yb[b,v,h] = sum_d W1a[h,d]*x[b,v,d] + b1[1,h]      (f32)
//   Zb[b,v,h] = sum_d W1b[h,d]*x[b,v,d]                (bf16)
// via mfma_f32_16x16x32_bf16 (M=64 rows=v, N=64 cols=h, K=64=d).
// block 64 packs W2[1] into per-lane MFMA B-fragment order:
//   wf2[((nt*2+ks)*64+lane)*8 + j] = W2[1][16*nt+(lane&15)][32*ks+8*(lane>>4)+j]
// ---------------------------------------------------------------------------
__global__ void prep2(const float* __restrict__ inputs,
                      const float* __restrict__ W1,
                      const float* __restrict__ b1,
                      const float* __restrict__ W2,
                      float* __restrict__ Yb,
                      bf16_t* __restrict__ Zb,
                      bf16_t* __restrict__ wf2) {
    const int blk = blockIdx.x;
    const int tid = threadIdx.x;
    if (blk == NB) {
        #pragma unroll
        for (int q = 0; q < 16; ++q) {
            int u = tid * 16 + q;
            int j = u & 7, lane = (u >> 3) & 63, ks = (u >> 9) & 1, nt = (u >> 10) & 3;
            int n = 16 * nt + (lane & 15);
            int h = 32 * ks + 8 * (lane >> 4) + j;
            wf2[u] = (bf16_t)W2[(NH + n) * NH + h];
        }
        return;
    }
    const int b = blk;
    const int lane = tid & 63, wid = tid >> 6, lr = lane & 15, lg = lane >> 4;

    // A fragments: X_b row (16*wid + lr), k-chunk 32*ks + 8*lg + j
    const float* xrow = inputs + (b * NV + 16 * wid + lr) * ND;
    bf16x8 a[2];
    #pragma unroll
    for (int ks = 0; ks < 2; ++ks) {
        f32x4 v0 = *(const f32x4*)(xrow + 32 * ks + 8 * lg);
        f32x4 v1 = *(const f32x4*)(xrow + 32 * ks + 8 * lg + 4);
        bf16x8 t;
        #pragma unroll
        for (int q = 0; q < 4; ++q) { t[q] = (bf16_t)v0[q]; t[4 + q] = (bf16_t)v1[q]; }
        a[ks] = t;
    }

    f32x4 accY[4], accZ[4];
    #pragma unroll
    for (int nt = 0; nt < 4; ++nt) {
        float base = b1[NH + 16 * nt + lr];
        accY[nt] = (f32x4){base, base, base, base};
        accZ[nt] = (f32x4){0.f, 0.f, 0.f, 0.f};
    }
    #pragma unroll
    for (int nt = 0; nt < 4; ++nt) {
        const float* wrow = W1 + (NH + 16 * nt + lr) * (2 * ND);  // W1[1][h=16nt+lr][:]
        #pragma unroll
        for (int ks = 0; ks < 2; ++ks) {
            f32x4 u0 = *(const f32x4*)(wrow + 32 * ks + 8 * lg);
            f32x4 u1 = *(const f32x4*)(wrow + 32 * ks + 8 * lg + 4);
            f32x4 w0 = *(const f32x4*)(wrow + 64 + 32 * ks + 8 * lg);
            f32x4 w1 = *(const f32x4*)(wrow + 64 + 32 * ks + 8 * lg + 4);
            bf16x8 by, bz;
            #pragma unroll
            for (int q = 0; q < 4; ++q) {
                by[q] = (bf16_t)u0[q]; by[4 + q] = (bf16_t)u1[q];
                bz[q] = (bf16_t)w0[q]; bz[4 + q] = (bf16_t)w1[q];
            }
            accY[nt] = __builtin_amdgcn_mfma_f32_16x16x32_bf16(a[ks], by, accY[nt], 0, 0, 0);
            accZ[nt] = __builtin_amdgcn_mfma_f32_16x16x32_bf16(a[ks], bz, accZ[nt], 0, 0, 0);
        }
    }
    // D layout: col = 16*nt + lr, row-in-tile = 4*lg + j  -> v = 16*wid + 4*lg + j
    #pragma unroll
    for (int nt = 0; nt < 4; ++nt) {
        #pragma unroll
        for (int j = 0; j < 4; ++j) {
            int v = 16 * wid + 4 * lg + j;
            Yb[(b * NV + v) * NH + 16 * nt + lr] = accY[nt][j];
            Zb[(b * NV + v) * NH + 16 * nt + lr] = (bf16_t)accZ[nt][j];
        }
    }
}

// ---------------------------------------------------------------------------
// gnn_main2: ONE WAVE per (b, r).  64 rows = 63 senders + 1 pad (weight 0),
// iterated as 4 M-tiles of 16.  msg1 = relu(Y[r] + Z[s]) built in-register;
// GEMM2 (8 MFMAs/tile) -> relu -> * edge weight -> row-reduce in registers.
// No LDS, no barriers; cross-lane only via 2 shfl_xor at the end.
// ---------------------------------------------------------------------------
__global__ __launch_bounds__(64, 4)
void gnn_main2(const float* __restrict__ inputs,
               const float* __restrict__ edges,
               const float* __restrict__ b2,
               const float* __restrict__ Yb,
               const bf16_t* __restrict__ Zb,
               const bf16_t* __restrict__ wf2,
               float* __restrict__ out) {
    const int bid = blockIdx.x;
    const int b = bid >> 6, r = bid & 63;
    const int lane = threadIdx.x;
    const int lr = lane & 15, lg = lane >> 4;

    // W2 fragments, loaded once, reused across all 4 M-tiles (broadcast, L1)
    bf16x8 wb[4][2];
    #pragma unroll
    for (int nt = 0; nt < 4; ++nt)
        #pragma unroll
        for (int ks = 0; ks < 2; ++ks)
            wb[nt][ks] = *(const bf16x8*)(wf2 + ((nt * 2 + ks) * 64 + lane) * 8);

    // Y row for this receiver (b1 already baked in), f32, broadcast across lr
    const float* ybr = Yb + (b * NV + r) * NH;
    f32x4 y[2][2];
    #pragma unroll
    for (int ks = 0; ks < 2; ++ks) {
        y[ks][0] = *(const f32x4*)(ybr + 32 * ks + 8 * lg);
        y[ks][1] = *(const f32x4*)(ybr + 32 * ks + 8 * lg + 4);
    }

    float base[4];
    #pragma unroll
    for (int nt = 0; nt < 4; ++nt) base[nt] = b2[NH + 16 * nt + lr];

    const bf16_t* zb = Zb + b * NV * NH;
    const float* eb = edges + b * NE * 2;

    float psum[4] = {0.f, 0.f, 0.f, 0.f};

    #pragma unroll
    for (int mt = 0; mt < 4; ++mt) {
        const int m = 16 * mt + lr;
        const int s = (m < r) ? m : (m == 63 ? r : m + 1);  // pad row -> s=r, weight 0

        // A fragment: msg1[m][32*ks+8*lg+j] = relu(Z[s][k] + Y[r][k])
        bf16x8 afr[2];
        #pragma unroll
        for (int ks = 0; ks < 2; ++ks) {
            bf16x8 z = *(const bf16x8*)(zb + s * NH + 32 * ks + 8 * lg);
            bf16x8 t;
            #pragma unroll
            for (int q = 0; q < 8; ++q) {
                float vv = (float)z[q] + y[ks][q >> 2][q & 3];
                t[q] = (bf16_t)(vv > 0.f ? vv : 0.f);
            }
            afr[ks] = t;
        }

        // edge weights for this lane's epilogue rows: me = 16*mt + 4*lg + j
        float wj[4];
        #pragma unroll
        for (int j = 0; j < 4; ++j) {
            int me = 16 * mt + 4 * lg + j;
            float w = 0.f;
            if (me < 63) {
                int se = (me < r) ? me : me + 1;
                int e = se * 63 + r - (se < r ? 1 : 0);
                w = eb[e * 2 + 1];
            }
            wj[j] = w;
        }

        #pragma unroll
        for (int nt = 0; nt < 4; ++nt) {
            f32x4 acc = (f32x4){base[nt], base[nt], base[nt], base[nt]};
            acc = __builtin_amdgcn_mfma_f32_16x16x32_bf16(afr[0], wb[nt][0], acc, 0, 0, 0);
            acc = __builtin_amdgcn_mfma_f32_16x16x32_bf16(afr[1], wb[nt][1], acc, 0, 0, 0);
            float ss = 0.f;
            #pragma unroll
            for (int j = 0; j < 4; ++j) {
                float v = acc[j];
                v = v > 0.f ? v : 0.f;
                ss = fmaf(v, wj[j], ss);
            }
            psum[nt] += ss;
        }
    }

    // sum partials across the 4 lg groups (rows were split by lg)
    #pragma unroll
    for (int nt = 0; nt < 4; ++nt) {
        psum[nt] += __shfl_xor(psum[nt], 16);
        psum[nt] += __shfl_xor(psum[nt], 32);
    }

    float* o = out + (b * NV + r) * OUTW;
    o[lane] = inputs[(b * NV + r) * ND + lane];          // concat: x
    // agg col = lane = 16*lg + lr  ->  psum[lg]
    float v = (lg == 0) ? psum[0] : (lg == 1) ? psum[1] : (lg == 2) ? psum[2] : psum[3];
    o[ND + lane] = v;
}

extern "C" void kernel_launch(void* const* d_in, const int* in_sizes, int n_in,
                              void* d_out, int out_size, void* d_ws, size_t ws_size,
                              hipStream_t stream) {
    const float* inputs = (const float*)d_in[0];
    const float* edges  = (const float*)d_in[1];
    const float* W1     = (const float*)d_in[2];
    const float* b1     = (const float*)d_in[3];
    const float* W2     = (const float*)d_in[4];
    const float* b2     = (const float*)d_in[5];
    // send_idx / recv_idx derived analytically.

    float*  Yb  = (float*)d_ws;                 // 64*64*64 f32 = 1 MB
    bf16_t* Zb  = (bf16_t*)(Yb + NB * NV * NH); // 512 KB
    bf16_t* wf2 = Zb + NB * NV * NH;            // 8 KB
    float*  out = (float*)d_out;

    prep2<<<NB + 1, 256, 0, stream>>>(inputs, W1, b1, W2, Yb, Zb, wf2);
    gnn_main2<<<NB * NV, 64, 0, stream>>>(inputs, edges, b2, Yb, Zb, wf2, out);
}

// Round 3
// 22.480 us; speedup vs baseline: 1.5437x; 1.0628x over previous
//
#include <hip/hip_runtime.h>
#include <hip/hip_bf16.h>

#define NB 64
#define NV 64
#define ND 64
#define NH 64
#define NE 4032   // V*(V-1)
#define OUTW 128  // D + H

typedef __bf16 bf16_t;
typedef bf16_t bf16x8 __attribute__((ext_vector_type(8)));
typedef float f32x4 __attribute__((ext_vector_type(4)));

// ---------------------------------------------------------------------------
// Single fused kernel.  Grid: 512 blocks = 8 per batch (oct = blk&7), each
// block owns 8 receivers (2 per wave).  Per block:
//   phase 1 (redundant per-b prep, cheap):
//     Ylds[v,h] = W1a[h,:]·x[b,v,:] + b1[1,h]   (f32, +1 pad col)
//     Zlds[v,h] = W1b[h,:]·x[b,v,:]             (bf16, +8 pad cols)
//     EW[e]     = edges[b,e,1]                  (coalesced float2 stage)
//     wb[nt][ks]= W2[1] B-fragments (regs)      b2 -> base2
//   phase 2 (per receiver r):
//     msg1[m,:] = relu(Y[r,:] + Z[s(m),:])  built in-register
//     msg2      = relu(msg1·W2^T + b2)      8 MFMAs per 16-row M-tile
//     agg[r,:] += sum_m msg2[m,:]*EW[e(m,r)]  register reduce + 2 shfl_xor
// MFMA layouts (verified rounds 0-2):
//   A: row = lane&15 (in tile), k = 32*ks + 8*(lane>>4) + j
//   B: col = lane&15,           k = 32*ks + 8*(lane>>4) + j
//   D: col = lane&15,           row = 4*(lane>>4) + j
// ---------------------------------------------------------------------------
__global__ __launch_bounds__(256, 2)
void gnn_fused(const float* __restrict__ inputs,
               const float* __restrict__ edges,
               const float* __restrict__ W1,
               const float* __restrict__ b1,
               const float* __restrict__ W2,
               const float* __restrict__ b2,
               float* __restrict__ out) {
    __shared__ float  Ylds[NV][NH + 1];   // 16.6 KB, pad breaks store conflicts
    __shared__ bf16_t Zlds[NV][NH + 8];   // 9.2 KB, 144B row stride -> 2-way reads
    __shared__ float  EW[NE];             // 16.1 KB

    const int blk = blockIdx.x;
    const int b = blk >> 3, oct = blk & 7;
    const int tid = threadIdx.x;
    const int lane = tid & 63, wid = tid >> 6;
    const int lr = lane & 15, lg = lane >> 4;

    // ---- stage edge-type-1 weights for batch b (coalesced 8B loads)
    const float2* e2 = (const float2*)(edges + b * NE * 2);
    #pragma unroll
    for (int i = 0; i < 16; ++i) {
        int e = i * 256 + tid;
        if (e < NE) EW[e] = e2[e].y;
    }

    // ---- W2[1] fragments + b2 into registers (L2-hot, reused all phase 2)
    bf16x8 wb[4][2];
    float base2[4];
    #pragma unroll
    for (int nt = 0; nt < 4; ++nt) {
        base2[nt] = b2[NH + 16 * nt + lr];
        const float* w2row = W2 + (NH + 16 * nt + lr) * NH;
        #pragma unroll
        for (int ks = 0; ks < 2; ++ks) {
            f32x4 v0 = *(const f32x4*)(w2row + 32 * ks + 8 * lg);
            f32x4 v1 = *(const f32x4*)(w2row + 32 * ks + 8 * lg + 4);
            bf16x8 t;
            #pragma unroll
            for (int q = 0; q < 4; ++q) { t[q] = (bf16_t)v0[q]; t[4 + q] = (bf16_t)v1[q]; }
            wb[nt][ks] = t;
        }
    }

    // ---- phase 1: Y/Z for all 64 nodes of b (wave wid owns rows 16*wid+lr)
    {
        const float* xrow = inputs + (b * NV + 16 * wid + lr) * ND;
        bf16x8 a[2];
        #pragma unroll
        for (int ks = 0; ks < 2; ++ks) {
            f32x4 v0 = *(const f32x4*)(xrow + 32 * ks + 8 * lg);
            f32x4 v1 = *(const f32x4*)(xrow + 32 * ks + 8 * lg + 4);
            bf16x8 t;
            #pragma unroll
            for (int q = 0; q < 4; ++q) { t[q] = (bf16_t)v0[q]; t[4 + q] = (bf16_t)v1[q]; }
            a[ks] = t;
        }

        f32x4 accY[4], accZ[4];
        #pragma unroll
        for (int nt = 0; nt < 4; ++nt) {
            float base = b1[NH + 16 * nt + lr];
            accY[nt] = (f32x4){base, base, base, base};
            accZ[nt] = (f32x4){0.f, 0.f, 0.f, 0.f};
        }
        #pragma unroll
        for (int nt = 0; nt < 4; ++nt) {
            const float* wrow = W1 + (NH + 16 * nt + lr) * (2 * ND);
            #pragma unroll
            for (int ks = 0; ks < 2; ++ks) {
                f32x4 u0 = *(const f32x4*)(wrow + 32 * ks + 8 * lg);
                f32x4 u1 = *(const f32x4*)(wrow + 32 * ks + 8 * lg + 4);
                f32x4 w0 = *(const f32x4*)(wrow + 64 + 32 * ks + 8 * lg);
                f32x4 w1 = *(const f32x4*)(wrow + 64 + 32 * ks + 8 * lg + 4);
                bf16x8 by, bz;
                #pragma unroll
                for (int q = 0; q < 4; ++q) {
                    by[q] = (bf16_t)u0[q]; by[4 + q] = (bf16_t)u1[q];
                    bz[q] = (bf16_t)w0[q]; bz[4 + q] = (bf16_t)w1[q];
                }
                accY[nt] = __builtin_amdgcn_mfma_f32_16x16x32_bf16(a[ks], by, accY[nt], 0, 0, 0);
                accZ[nt] = __builtin_amdgcn_mfma_f32_16x16x32_bf16(a[ks], bz, accZ[nt], 0, 0, 0);
            }
        }
        #pragma unroll
        for (int nt = 0; nt < 4; ++nt) {
            #pragma unroll
            for (int j = 0; j < 4; ++j) {
                int v = 16 * wid + 4 * lg + j;
                Ylds[v][16 * nt + lr] = accY[nt][j];
                Zlds[v][16 * nt + lr] = (bf16_t)accZ[nt][j];
            }
        }
    }
    __syncthreads();

    // ---- phase 2: two receivers per wave
    #pragma unroll
    for (int rr = 0; rr < 2; ++rr) {
        const int r = oct * 8 + wid * 2 + rr;

        f32x4 y[2][2];
        #pragma unroll
        for (int ks = 0; ks < 2; ++ks) {
            y[ks][0] = *(const f32x4*)(&Ylds[r][32 * ks + 8 * lg]);
            y[ks][1] = *(const f32x4*)(&Ylds[r][32 * ks + 8 * lg + 4]);
        }

        float psum[4] = {0.f, 0.f, 0.f, 0.f};

        #pragma unroll
        for (int mt = 0; mt < 4; ++mt) {
            const int m = 16 * mt + lr;
            const int s = (m < r) ? m : (m == 63 ? r : m + 1);  // pad row: weight 0

            bf16x8 afr[2];
            #pragma unroll
            for (int ks = 0; ks < 2; ++ks) {
                bf16x8 z = *(const bf16x8*)(&Zlds[s][32 * ks + 8 * lg]);
                bf16x8 t;
                #pragma unroll
                for (int q = 0; q < 8; ++q) {
                    float vv = (float)z[q] + y[ks][q >> 2][q & 3];
                    t[q] = (bf16_t)(vv > 0.f ? vv : 0.f);
                }
                afr[ks] = t;
            }

            float wj[4];
            #pragma unroll
            for (int j = 0; j < 4; ++j) {
                int me = 16 * mt + 4 * lg + j;
                float w = 0.f;
                if (me < 63) {
                    int se = (me < r) ? me : me + 1;
                    w = EW[se * 63 + r - (se < r ? 1 : 0)];
                }
                wj[j] = w;
            }

            #pragma unroll
            for (int nt = 0; nt < 4; ++nt) {
                f32x4 acc = (f32x4){base2[nt], base2[nt], base2[nt], base2[nt]};
                acc = __builtin_amdgcn_mfma_f32_16x16x32_bf16(afr[0], wb[nt][0], acc, 0, 0, 0);
                acc = __builtin_amdgcn_mfma_f32_16x16x32_bf16(afr[1], wb[nt][1], acc, 0, 0, 0);
                float ss = 0.f;
                #pragma unroll
                for (int j = 0; j < 4; ++j) {
                    float v = acc[j];
                    v = v > 0.f ? v : 0.f;
                    ss = fmaf(v, wj[j], ss);
                }
                psum[nt] += ss;
            }
        }

        #pragma unroll
        for (int nt = 0; nt < 4; ++nt) {
            psum[nt] += __shfl_xor(psum[nt], 16);
            psum[nt] += __shfl_xor(psum[nt], 32);
        }

        float* o = out + (b * NV + r) * OUTW;
        o[lane] = inputs[(b * NV + r) * ND + lane];
        float v = (lg == 0) ? psum[0] : (lg == 1) ? psum[1] : (lg == 2) ? psum[2] : psum[3];
        o[ND + lane] = v;
    }
}

extern "C" void kernel_launch(void* const* d_in, const int* in_sizes, int n_in,
                              void* d_out, int out_size, void* d_ws, size_t ws_size,
                              hipStream_t stream) {
    const float* inputs = (const float*)d_in[0];
    const float* edges  = (const float*)d_in[1];
    const float* W1     = (const float*)d_in[2];
    const float* b1     = (const float*)d_in[3];
    const float* W2     = (const float*)d_in[4];
    const float* b2     = (const float*)d_in[5];
    // send_idx / recv_idx derived analytically.

    gnn_fused<<<NB * 8, 256, 0, stream>>>(inputs, edges, W1, b1, W2, b2, (float*)d_out);
}

// Round 4
// 20.895 us; speedup vs baseline: 1.6609x; 1.0759x over previous
//
#include <hip/hip_runtime.h>
#include <hip/hip_bf16.h>

#define NB 64
#define NV 64
#define ND 64
#define NH 64
#define NE 4032   // V*(V-1)
#define OUTW 128  // D + H

typedef __bf16 bf16_t;
typedef bf16_t bf16x8 __attribute__((ext_vector_type(8)));
typedef float f32x4 __attribute__((ext_vector_type(4)));

// ---------------------------------------------------------------------------
// Single fused kernel.  Grid: 256 blocks = 4 per batch (quad = blk&3), 8 waves
// each; each wave owns 2 receivers (16 per block).  Per block:
//   phase 1 (per-b prep, waves split the work):
//     waves 0-3: Ylds[v,h] = W1a[h,:]·x[b,v,:] + b1[1,h]   (f32, +1 pad col)
//     waves 4-7: Zlds[v,h] = W1b[h,:]·x[b,v,:]             (bf16, +8 pad cols)
//     EW[e]     = edges[b,e,1]                  (coalesced float2 stage)
//     wb[nt][ks]= W2[1] B-fragments (regs), b2 -> base2
//   phase 2 (per receiver r = quad*16 + wid*2 + rr):
//     msg1[m,:] = relu(Y[r,:] + Z[s(m),:])  built in-register
//     msg2      = relu(msg1·W2^T + b2)      8 MFMAs per 16-row M-tile
//     agg[r,:] += sum_m msg2[m,:]*EW[e(m,r)]  register reduce + 2 shfl_xor
// MFMA layouts (verified rounds 0-3):
//   A: row = lane&15 (in tile), k = 32*ks + 8*(lane>>4) + j
//   B: col = lane&15,           k = 32*ks + 8*(lane>>4) + j
//   D: col = lane&15,           row = 4*(lane>>4) + j
// ---------------------------------------------------------------------------
__global__ __launch_bounds__(512, 1)
void gnn_fused(const float* __restrict__ inputs,
               const float* __restrict__ edges,
               const float* __restrict__ W1,
               const float* __restrict__ b1,
               const float* __restrict__ W2,
               const float* __restrict__ b2,
               float* __restrict__ out) {
    __shared__ float  Ylds[NV][NH + 1];   // 16.6 KB
    __shared__ bf16_t Zlds[NV][NH + 8];   // 9.2 KB, 144B row stride -> 2-way reads
    __shared__ float  EW[NE];             // 16.1 KB

    const int blk = blockIdx.x;
    const int b = blk >> 2, quad = blk & 3;
    const int tid = threadIdx.x;
    const int lane = tid & 63, wid = tid >> 6;
    const int lr = lane & 15, lg = lane >> 4;

    // ---- stage edge-type-1 weights for batch b (coalesced 8B loads)
    const float2* e2 = (const float2*)(edges + b * NE * 2);
    #pragma unroll
    for (int i = 0; i < 8; ++i) {
        int e = i * 512 + tid;
        if (e < NE) EW[e] = e2[e].y;
    }

    // ---- W2[1] fragments + b2 into registers (L1/L2-hot, reused all phase 2)
    bf16x8 wb[4][2];
    float base2[4];
    #pragma unroll
    for (int nt = 0; nt < 4; ++nt) {
        base2[nt] = b2[NH + 16 * nt + lr];
        const float* w2row = W2 + (NH + 16 * nt + lr) * NH;
        #pragma unroll
        for (int ks = 0; ks < 2; ++ks) {
            f32x4 v0 = *(const f32x4*)(w2row + 32 * ks + 8 * lg);
            f32x4 v1 = *(const f32x4*)(w2row + 32 * ks + 8 * lg + 4);
            bf16x8 t;
            #pragma unroll
            for (int q = 0; q < 4; ++q) { t[q] = (bf16_t)v0[q]; t[4 + q] = (bf16_t)v1[q]; }
            wb[nt][ks] = t;
        }
    }

    // ---- phase 1: waves 0-3 compute Y rows, waves 4-7 compute Z rows
    {
        const int half = wid >> 2;          // 0: Y (W1a, +b1), 1: Z (W1b)
        const int wt = wid & 3;             // row tile: rows 16*wt + lr
        const int hoff = half * ND;         // column offset into W1[1] rows

        const float* xrow = inputs + (b * NV + 16 * wt + lr) * ND;
        bf16x8 a[2];
        #pragma unroll
        for (int ks = 0; ks < 2; ++ks) {
            f32x4 v0 = *(const f32x4*)(xrow + 32 * ks + 8 * lg);
            f32x4 v1 = *(const f32x4*)(xrow + 32 * ks + 8 * lg + 4);
            bf16x8 t;
            #pragma unroll
            for (int q = 0; q < 4; ++q) { t[q] = (bf16_t)v0[q]; t[4 + q] = (bf16_t)v1[q]; }
            a[ks] = t;
        }

        f32x4 acc[4];
        #pragma unroll
        for (int nt = 0; nt < 4; ++nt) {
            float base = (half == 0) ? b1[NH + 16 * nt + lr] : 0.f;
            acc[nt] = (f32x4){base, base, base, base};
        }
        #pragma unroll
        for (int nt = 0; nt < 4; ++nt) {
            const float* wrow = W1 + (NH + 16 * nt + lr) * (2 * ND) + hoff;
            #pragma unroll
            for (int ks = 0; ks < 2; ++ks) {
                f32x4 u0 = *(const f32x4*)(wrow + 32 * ks + 8 * lg);
                f32x4 u1 = *(const f32x4*)(wrow + 32 * ks + 8 * lg + 4);
                bf16x8 bw;
                #pragma unroll
                for (int q = 0; q < 4; ++q) { bw[q] = (bf16_t)u0[q]; bw[4 + q] = (bf16_t)u1[q]; }
                acc[nt] = __builtin_amdgcn_mfma_f32_16x16x32_bf16(a[ks], bw, acc[nt], 0, 0, 0);
            }
        }
        #pragma unroll
        for (int nt = 0; nt < 4; ++nt) {
            #pragma unroll
            for (int j = 0; j < 4; ++j) {
                int v = 16 * wt + 4 * lg + j;
                if (half == 0) Ylds[v][16 * nt + lr] = acc[nt][j];
                else           Zlds[v][16 * nt + lr] = (bf16_t)acc[nt][j];
            }
        }
    }
    __syncthreads();

    // ---- phase 2: two receivers per wave
    #pragma unroll
    for (int rr = 0; rr < 2; ++rr) {
        const int r = quad * 16 + wid * 2 + rr;

        f32x4 y[2][2];
        #pragma unroll
        for (int ks = 0; ks < 2; ++ks) {
            y[ks][0] = *(const f32x4*)(&Ylds[r][32 * ks + 8 * lg]);
            y[ks][1] = *(const f32x4*)(&Ylds[r][32 * ks + 8 * lg + 4]);
        }

        float psum[4] = {0.f, 0.f, 0.f, 0.f};

        #pragma unroll
        for (int mt = 0; mt < 4; ++mt) {
            const int m = 16 * mt + lr;
            const int s = (m < r) ? m : (m == 63 ? r : m + 1);  // pad row: weight 0

            bf16x8 afr[2];
            #pragma unroll
            for (int ks = 0; ks < 2; ++ks) {
                bf16x8 z = *(const bf16x8*)(&Zlds[s][32 * ks + 8 * lg]);
                bf16x8 t;
                #pragma unroll
                for (int q = 0; q < 8; ++q) {
                    float vv = (float)z[q] + y[ks][q >> 2][q & 3];
                    t[q] = (bf16_t)(vv > 0.f ? vv : 0.f);
                }
                afr[ks] = t;
            }

            float wj[4];
            #pragma unroll
            for (int j = 0; j < 4; ++j) {
                int me = 16 * mt + 4 * lg + j;
                float w = 0.f;
                if (me < 63) {
                    int se = (me < r) ? me : me + 1;
                    w = EW[se * 63 + r - (se < r ? 1 : 0)];
                }
                wj[j] = w;
            }

            #pragma unroll
            for (int nt = 0; nt < 4; ++nt) {
                f32x4 acc = (f32x4){base2[nt], base2[nt], base2[nt], base2[nt]};
                acc = __builtin_amdgcn_mfma_f32_16x16x32_bf16(afr[0], wb[nt][0], acc, 0, 0, 0);
                acc = __builtin_amdgcn_mfma_f32_16x16x32_bf16(afr[1], wb[nt][1], acc, 0, 0, 0);
                float ss = 0.f;
                #pragma unroll
                for (int j = 0; j < 4; ++j) {
                    float v = acc[j];
                    v = v > 0.f ? v : 0.f;
                    ss = fmaf(v, wj[j], ss);
                }
                psum[nt] += ss;
            }
        }

        #pragma unroll
        for (int nt = 0; nt < 4; ++nt) {
            psum[nt] += __shfl_xor(psum[nt], 16);
            psum[nt] += __shfl_xor(psum[nt], 32);
        }

        float* o = out + (b * NV + r) * OUTW;
        o[lane] = inputs[(b * NV + r) * ND + lane];
        float v = (lg == 0) ? psum[0] : (lg == 1) ? psum[1] : (lg == 2) ? psum[2] : psum[3];
        o[ND + lane] = v;
    }
}

extern "C" void kernel_launch(void* const* d_in, const int* in_sizes, int n_in,
                              void* d_out, int out_size, void* d_ws, size_t ws_size,
                              hipStream_t stream) {
    const float* inputs = (const float*)d_in[0];
    const float* edges  = (const float*)d_in[1];
    const float* W1     = (const float*)d_in[2];
    const float* b1     = (const float*)d_in[3];
    const float* W2     = (const float*)d_in[4];
    const float* b2     = (const float*)d_in[5];
    // send_idx / recv_idx derived analytically.

    gnn_fused<<<NB * 4, 512, 0, stream>>>(inputs, edges, W1, b1, W2, b2, (float*)d_out);
}

// Round 6
// 20.772 us; speedup vs baseline: 1.6707x; 1.0059x over previous
//
#include <hip/hip_runtime.h>
#include <hip/hip_bf16.h>

#define NB 64
#define NV 64
#define ND 64
#define NH 64
#define NE 4032   // V*(V-1)
#define OUTW 128  // D + H

typedef __bf16 bf16_t;
typedef bf16_t bf16x8 __attribute__((ext_vector_type(8)));
typedef float f32x4 __attribute__((ext_vector_type(4)));
typedef short s16x8 __attribute__((ext_vector_type(8)));

// ---------------------------------------------------------------------------
// Single fused kernel.  Grid: 256 blocks = 4 per batch (quad = blk&3), 8 waves
// each; each wave owns 2 receivers (16 per block).  Per block:
//   phase 1 (per-b prep, waves split the work):
//     waves 0-3: Ylds[v,h] = bf16(W1a[h,:]·x[b,v,:] + b1[1,h])
//     waves 4-7: Zlds[v,h] = bf16(W1b[h,:]·x[b,v,:])
//     EW[e]     = edges[b,e,1]                  (coalesced float2 stage)
//     wb[nt][ks]= W2[1] B-fragments (regs), b2 -> base2
//   phase 2 (per receiver r = quad*16 + wid*2 + rr):
//     msg1[m,:] = relu(Y[r,:] + Z[s(m),:])  -- v_pk_add_bf16 + sign-mask relu
//     msg2      = relu(msg1·W2^T + b2)      8 MFMAs per 16-row M-tile
//     agg[r,:] += sum_m msg2[m,:]*EW[e(m,r)]  register reduce + 2 shfl_xor
// MFMA layouts (verified rounds 0-4):
//   A: row = lane&15 (in tile), k = 32*ks + 8*(lane>>4) + j
//   B: col = lane&15,           k = 32*ks + 8*(lane>>4) + j
//   D: col = lane&15,           row = 4*(lane>>4) + j
// ---------------------------------------------------------------------------
__global__ __launch_bounds__(512, 1)
void gnn_fused(const float* __restrict__ inputs,
               const float* __restrict__ edges,
               const float* __restrict__ W1,
               const float* __restrict__ b1,
               const float* __restrict__ W2,
               const float* __restrict__ b2,
               float* __restrict__ out) {
    __shared__ bf16_t Ylds[NV][NH + 8];   // 9.2 KB, 144B row stride
    __shared__ bf16_t Zlds[NV][NH + 8];   // 9.2 KB
    __shared__ float  EW[NE];             // 16.1 KB

    const int blk = blockIdx.x;
    const int b = blk >> 2, quad = blk & 3;
    const int tid = threadIdx.x;
    const int lane = tid & 63, wid = tid >> 6;
    const int lr = lane & 15, lg = lane >> 4;

    // ---- stage edge-type-1 weights for batch b (coalesced 8B loads)
    const float2* e2 = (const float2*)(edges + b * NE * 2);
    #pragma unroll
    for (int i = 0; i < 8; ++i) {
        int e = i * 512 + tid;
        if (e < NE) EW[e] = e2[e].y;
    }

    // ---- W2[1] fragments + b2 into registers (L1/L2-hot, reused all phase 2)
    bf16x8 wb[4][2];
    float base2[4];
    #pragma unroll
    for (int nt = 0; nt < 4; ++nt) {
        base2[nt] = b2[NH + 16 * nt + lr];
        const float* w2row = W2 + (NH + 16 * nt + lr) * NH;
        #pragma unroll
        for (int ks = 0; ks < 2; ++ks) {
            f32x4 v0 = *(const f32x4*)(w2row + 32 * ks + 8 * lg);
            f32x4 v1 = *(const f32x4*)(w2row + 32 * ks + 8 * lg + 4);
            bf16x8 t;
            #pragma unroll
            for (int q = 0; q < 4; ++q) { t[q] = (bf16_t)v0[q]; t[4 + q] = (bf16_t)v1[q]; }
            wb[nt][ks] = t;
        }
    }

    // ---- phase 1: waves 0-3 compute Y rows, waves 4-7 compute Z rows
    {
        const int half = wid >> 2;          // 0: Y (W1a, +b1), 1: Z (W1b)
        const int wt = wid & 3;             // row tile: rows 16*wt + lr
        const int hoff = half * ND;         // column offset into W1[1] rows

        const float* xrow = inputs + (b * NV + 16 * wt + lr) * ND;
        bf16x8 a[2];
        #pragma unroll
        for (int ks = 0; ks < 2; ++ks) {
            f32x4 v0 = *(const f32x4*)(xrow + 32 * ks + 8 * lg);
            f32x4 v1 = *(const f32x4*)(xrow + 32 * ks + 8 * lg + 4);
            bf16x8 t;
            #pragma unroll
            for (int q = 0; q < 4; ++q) { t[q] = (bf16_t)v0[q]; t[4 + q] = (bf16_t)v1[q]; }
            a[ks] = t;
        }

        f32x4 acc[4];
        #pragma unroll
        for (int nt = 0; nt < 4; ++nt) {
            float base = (half == 0) ? b1[NH + 16 * nt + lr] : 0.f;
            acc[nt] = (f32x4){base, base, base, base};
        }
        #pragma unroll
        for (int nt = 0; nt < 4; ++nt) {
            const float* wrow = W1 + (NH + 16 * nt + lr) * (2 * ND) + hoff;
            #pragma unroll
            for (int ks = 0; ks < 2; ++ks) {
                f32x4 u0 = *(const f32x4*)(wrow + 32 * ks + 8 * lg);
                f32x4 u1 = *(const f32x4*)(wrow + 32 * ks + 8 * lg + 4);
                bf16x8 bw;
                #pragma unroll
                for (int q = 0; q < 4; ++q) { bw[q] = (bf16_t)u0[q]; bw[4 + q] = (bf16_t)u1[q]; }
                acc[nt] = __builtin_amdgcn_mfma_f32_16x16x32_bf16(a[ks], bw, acc[nt], 0, 0, 0);
            }
        }
        #pragma unroll
        for (int nt = 0; nt < 4; ++nt) {
            #pragma unroll
            for (int j = 0; j < 4; ++j) {
                int v = 16 * wt + 4 * lg + j;
                if (half == 0) Ylds[v][16 * nt + lr] = (bf16_t)acc[nt][j];
                else           Zlds[v][16 * nt + lr] = (bf16_t)acc[nt][j];
            }
        }
    }
    __syncthreads();

    // ---- phase 2: two receivers per wave
    #pragma unroll
    for (int rr = 0; rr < 2; ++rr) {
        const int r = quad * 16 + wid * 2 + rr;

        // Y row fragment for this receiver (bf16, broadcast within lg groups)
        bf16x8 y8[2];
        #pragma unroll
        for (int ks = 0; ks < 2; ++ks)
            y8[ks] = *(const bf16x8*)(&Ylds[r][32 * ks + 8 * lg]);

        float psum[4] = {0.f, 0.f, 0.f, 0.f};

        #pragma unroll
        for (int mt = 0; mt < 4; ++mt) {
            const int m = 16 * mt + lr;
            const int s = (m < r) ? m : (m == 63 ? r : m + 1);  // pad row: weight 0

            // A fragment: relu(Z[s] + Y[r]) -- packed bf16 add + sign-mask relu
            bf16x8 afr[2];
            #pragma unroll
            for (int ks = 0; ks < 2; ++ks) {
                bf16x8 z = *(const bf16x8*)(&Zlds[s][32 * ks + 8 * lg]);
                bf16x8 tsum = z + y8[ks];                 // v_pk_add_bf16
                s16x8 sv = __builtin_bit_cast(s16x8, tsum);
                sv &= ~(sv >> 15);                        // zero negatives (relu)
                afr[ks] = __builtin_bit_cast(bf16x8, sv);
            }

            float wj[4];
            #pragma unroll
            for (int j = 0; j < 4; ++j) {
                int me = 16 * mt + 4 * lg + j;
                float w = 0.f;
                if (me < 63) {
                    int se = (me < r) ? me : me + 1;
                    w = EW[se * 63 + r - (se < r ? 1 : 0)];
                }
                wj[j] = w;
            }

            #pragma unroll
            for (int nt = 0; nt < 4; ++nt) {
                f32x4 acc = (f32x4){base2[nt], base2[nt], base2[nt], base2[nt]};
                acc = __builtin_amdgcn_mfma_f32_16x16x32_bf16(afr[0], wb[nt][0], acc, 0, 0, 0);
                acc = __builtin_amdgcn_mfma_f32_16x16x32_bf16(afr[1], wb[nt][1], acc, 0, 0, 0);
                float ss = 0.f;
                #pragma unroll
                for (int j = 0; j < 4; ++j) {
                    float v = acc[j];
                    v = v > 0.f ? v : 0.f;
                    ss = fmaf(v, wj[j], ss);
                }
                psum[nt] += ss;
            }
        }

        #pragma unroll
        for (int nt = 0; nt < 4; ++nt) {
            psum[nt] += __shfl_xor(psum[nt], 16);
            psum[nt] += __shfl_xor(psum[nt], 32);
        }

        float* o = out + (b * NV + r) * OUTW;
        o[lane] = inputs[(b * NV + r) * ND + lane];
        float v = (lg == 0) ? psum[0] : (lg == 1) ? psum[1] : (lg == 2) ? psum[2] : psum[3];
        o[ND + lane] = v;
    }
}

extern "C" void kernel_launch(void* const* d_in, const int* in_sizes, int n_in,
                              void* d_out, int out_size, void* d_ws, size_t ws_size,
                              hipStream_t stream) {
    const float* inputs = (const float*)d_in[0];
    const float* edges  = (const float*)d_in[1];
    const float* W1     = (const float*)d_in[2];
    const float* b1     = (const float*)d_in[3];
    const float* W2     = (const float*)d_in[4];
    const float* b2     = (const float*)d_in[5];
    // send_idx / recv_idx derived analytically.

    gnn_fused<<<NB * 4, 512, 0, stream>>>(inputs, edges, W1, b1, W2, b2, (float*)d_out);
}